// Round 9
// baseline (688.403 us; speedup 1.0000x reference)
//
#include <hip/hip_runtime.h>
#include <hip/hip_cooperative_groups.h>
#include <stdint.h>

namespace cg = cooperative_groups;

// Sparse 3D avg-pool, kernel=stride=2, GRID=128, B=8, C=32.
// Round 9: fuse the 5-kernel prep chain (zero/count/blocksum/finalize/scatter)
// into ONE cooperative kernel with 4 grid.sync()s; fallback to the proven
// 5-kernel path if cooperative launch is unavailable. k_pool unchanged.

#define KS (1u << 21)            // 2,097,152 possible keys
#define KMASK (KS - 1u)
#define NBLK 1024
#define TPB 256
#define EPT 8                    // 256*8 = 2048 hist cells per block
#define C 32
#define UNROLL 8

typedef float vf4 __attribute__((ext_vector_type(4)));

// ================= cooperative fused prep =================
__global__ __launch_bounds__(TPB, 4)
void coop_prep(const int4* __restrict__ coords, uint32_t* __restrict__ keys,
               uint32_t* __restrict__ cnt, uint32_t* __restrict__ cur,
               uint64_t* __restrict__ denseMeta, float* __restrict__ uniqOut,
               uint32_t* __restrict__ totalK, uint32_t* __restrict__ sortedIdx,
               uint32_t* __restrict__ blkP, uint32_t* __restrict__ blkM, int n) {
  cg::grid_group grid = cg::this_grid();
  const int t = threadIdx.x;
  const int b = blockIdx.x;

  // ---- P0: zero histogram (2048 cells / block) ----
  {
    uint4 z = make_uint4(0u, 0u, 0u, 0u);
    uint4* p = (uint4*)cnt + b * 512;
    p[t] = z;
    p[t + 256] = z;
  }
  grid.sync();

  // ---- P1: key + histogram + rank ----
  const int chunk = (n + NBLK - 1) / NBLK;
  const int cbase = b * chunk;
  const int cend = (cbase + chunk < n) ? cbase + chunk : n;
  for (int i = cbase + t; i < cend; i += TPB) {
    int4 cc = coords[i];
    uint32_t k = (((uint32_t)cc.x * 64u + ((uint32_t)cc.y >> 1)) * 64u
                  + ((uint32_t)cc.z >> 1)) * 64u + ((uint32_t)cc.w >> 1);
    uint32_t r = atomicAdd(&cnt[k], 1u);
    keys[i] = k | (r << 21);
  }
  grid.sync();

  // ---- P2: per-block (presence, count) partial sums ----
  __shared__ uint32_t sp[TPB], sm[TPB];
  {
    int base = b * (TPB * EPT) + t * EPT;
    const uint4* c4 = (const uint4*)(cnt + base);
    uint4 q0 = c4[0], q1 = c4[1];
    uint32_t p = (q0.x > 0) + (q0.y > 0) + (q0.z > 0) + (q0.w > 0)
               + (q1.x > 0) + (q1.y > 0) + (q1.z > 0) + (q1.w > 0);
    uint32_t m = q0.x + q0.y + q0.z + q0.w + q1.x + q1.y + q1.z + q1.w;
    sp[t] = p; sm[t] = m;
    __syncthreads();
    for (int off = TPB / 2; off > 0; off >>= 1) {
      if (t < off) { sp[t] += sp[t + off]; sm[t] += sm[t + off]; }
      __syncthreads();
    }
    if (t == 0) { blkP[b] = sp[0]; blkM[b] = sm[0]; }
  }
  grid.sync();

  // ---- P3: finalize (global prefix via reduction of partials + intra scan) ----
  __shared__ uint64_t rAll[TPB], rBel[TPB];
  {
    uint64_t all = 0, bel = 0;
    for (int u = t; u < NBLK; u += TPB) {
      uint64_t v = ((uint64_t)blkP[u] << 32) | (uint64_t)blkM[u];
      all += v;
      if (u < b) bel += v;
    }
    rAll[t] = all; rBel[t] = bel;
    __syncthreads();
    for (int off = TPB / 2; off > 0; off >>= 1) {
      if (t < off) { rAll[t] += rAll[t + off]; rBel[t] += rBel[t + off]; }
      __syncthreads();
    }
    const uint32_t blockP = (uint32_t)(rBel[0] >> 32);
    const uint32_t blockM = (uint32_t)rBel[0];
    if (b == 0 && t == 0) *totalK = (uint32_t)(rAll[0] >> 32);
    __syncthreads();

    int base = b * (TPB * EPT) + t * EPT;
    const uint4* c4 = (const uint4*)(cnt + base);
    uint4 q0 = c4[0], q1 = c4[1];
    uint32_t c[EPT] = {q0.x, q0.y, q0.z, q0.w, q1.x, q1.y, q1.z, q1.w};
    uint32_t p = 0, m = 0;
#pragma unroll
    for (int e = 0; e < EPT; e++) { p += (c[e] > 0); m += c[e]; }
    sp[t] = p; sm[t] = m;
    __syncthreads();
    for (int off = 1; off < TPB; off <<= 1) {
      uint32_t vp = (t >= off) ? sp[t - off] : 0u;
      uint32_t vm = (t >= off) ? sm[t - off] : 0u;
      __syncthreads();
      sp[t] += vp; sm[t] += vm;
      __syncthreads();
    }
    uint32_t poff = blockP + (t ? sp[t - 1] : 0u);
    uint32_t moff = blockM + (t ? sm[t - 1] : 0u);
#pragma unroll
    for (int e = 0; e < EPT; e++) {
      if (c[e] > 0) {
        uint32_t k = (uint32_t)base + (uint32_t)e;
        cur[k] = moff;
        denseMeta[poff] = ((uint64_t)c[e] << 32) | (uint64_t)moff;
        uniqOut[poff] = (float)k;
        poff++;
      }
      moff += c[e];
    }
  }
  grid.sync();

  // ---- P4: atomic-free counting-sort placement ----
  for (int i = cbase + t; i < cend; i += TPB) {
    uint32_t kk = keys[i];
    sortedIdx[cur[kk & KMASK] + (kk >> 21)] = (uint32_t)i;
  }
}

// ================= fallback (proven R8) kernels =================
__global__ void k_zero(uint4* __restrict__ p, int n4) {
  int i = blockIdx.x * blockDim.x + threadIdx.x;
  if (i < n4) p[i] = make_uint4(0u, 0u, 0u, 0u);
}

__global__ void k_count(const int4* __restrict__ coords, uint32_t* __restrict__ keys,
                        uint32_t* __restrict__ cnt, int n) {
  const int base = blockIdx.x * (256 * UNROLL) + threadIdx.x;
  const bool full = (blockIdx.x + 1) * (256 * UNROLL) <= n;
  if (full) {
    int4 cc[UNROLL];
    uint32_t k[UNROLL], r[UNROLL];
#pragma unroll
    for (int u = 0; u < UNROLL; ++u) cc[u] = coords[base + u * 256];
#pragma unroll
    for (int u = 0; u < UNROLL; ++u)
      k[u] = (((uint32_t)cc[u].x * 64u + ((uint32_t)cc[u].y >> 1)) * 64u
              + ((uint32_t)cc[u].z >> 1)) * 64u + ((uint32_t)cc[u].w >> 1);
#pragma unroll
    for (int u = 0; u < UNROLL; ++u) r[u] = atomicAdd(&cnt[k[u]], 1u);
#pragma unroll
    for (int u = 0; u < UNROLL; ++u) keys[base + u * 256] = k[u] | (r[u] << 21);
  } else {
    for (int u = 0; u < UNROLL; ++u) {
      int i = base + u * 256;
      if (i < n) {
        int4 cc = coords[i];
        uint32_t k = (((uint32_t)cc.x * 64u + ((uint32_t)cc.y >> 1)) * 64u
                      + ((uint32_t)cc.z >> 1)) * 64u + ((uint32_t)cc.w >> 1);
        uint32_t r = atomicAdd(&cnt[k], 1u);
        keys[i] = k | (r << 21);
      }
    }
  }
}

__global__ void k_blocksum(const uint32_t* __restrict__ cnt,
                           uint32_t* __restrict__ blkP, uint32_t* __restrict__ blkM) {
  __shared__ uint32_t sp[TPB], sm[TPB];
  int t = threadIdx.x;
  int base = blockIdx.x * (TPB * EPT) + t * EPT;
  const uint4* c4 = (const uint4*)(cnt + base);
  uint4 q0 = c4[0], q1 = c4[1];
  uint32_t p = (q0.x > 0) + (q0.y > 0) + (q0.z > 0) + (q0.w > 0)
             + (q1.x > 0) + (q1.y > 0) + (q1.z > 0) + (q1.w > 0);
  uint32_t m = q0.x + q0.y + q0.z + q0.w + q1.x + q1.y + q1.z + q1.w;
  sp[t] = p; sm[t] = m;
  __syncthreads();
  for (int off = TPB / 2; off > 0; off >>= 1) {
    if (t < off) { sp[t] += sp[t + off]; sm[t] += sm[t + off]; }
    __syncthreads();
  }
  if (t == 0) { blkP[blockIdx.x] = sp[0]; blkM[blockIdx.x] = sm[0]; }
}

__global__ void k_finalize(const uint32_t* __restrict__ cnt,
                           const uint32_t* __restrict__ blkP, const uint32_t* __restrict__ blkM,
                           uint32_t* __restrict__ cur,
                           uint64_t* __restrict__ denseMeta,
                           float* __restrict__ uniqOut,
                           uint32_t* __restrict__ totalK) {
  __shared__ uint64_t rAll[TPB], rBel[TPB];
  __shared__ uint32_t sp[TPB], sm[TPB];
  const int t = threadIdx.x;
  const int b = blockIdx.x;
  uint64_t all = 0, bel = 0;
  for (int u = t; u < NBLK; u += TPB) {
    uint64_t v = ((uint64_t)blkP[u] << 32) | (uint64_t)blkM[u];
    all += v;
    if (u < b) bel += v;
  }
  rAll[t] = all; rBel[t] = bel;
  __syncthreads();
  for (int off = TPB / 2; off > 0; off >>= 1) {
    if (t < off) { rAll[t] += rAll[t + off]; rBel[t] += rBel[t + off]; }
    __syncthreads();
  }
  const uint32_t blockP = (uint32_t)(rBel[0] >> 32);
  const uint32_t blockM = (uint32_t)rBel[0];
  if (b == 0 && t == 0) *totalK = (uint32_t)(rAll[0] >> 32);

  int base = b * (TPB * EPT) + t * EPT;
  const uint4* c4 = (const uint4*)(cnt + base);
  uint4 q0 = c4[0], q1 = c4[1];
  uint32_t c[EPT] = {q0.x, q0.y, q0.z, q0.w, q1.x, q1.y, q1.z, q1.w};
  uint32_t p = 0, m = 0;
#pragma unroll
  for (int e = 0; e < EPT; e++) { p += (c[e] > 0); m += c[e]; }
  __syncthreads();
  sp[t] = p; sm[t] = m;
  __syncthreads();
  for (int off = 1; off < TPB; off <<= 1) {
    uint32_t vp = (t >= off) ? sp[t - off] : 0u;
    uint32_t vm = (t >= off) ? sm[t - off] : 0u;
    __syncthreads();
    sp[t] += vp; sm[t] += vm;
    __syncthreads();
  }
  uint32_t poff = blockP + (t ? sp[t - 1] : 0u);
  uint32_t moff = blockM + (t ? sm[t - 1] : 0u);
#pragma unroll
  for (int e = 0; e < EPT; e++) {
    if (c[e] > 0) {
      uint32_t k = (uint32_t)base + (uint32_t)e;
      cur[k] = moff;
      denseMeta[poff] = ((uint64_t)c[e] << 32) | (uint64_t)moff;
      uniqOut[poff] = (float)k;
      poff++;
    }
    moff += c[e];
  }
}

__global__ void k_scatter(const uint32_t* __restrict__ keys, const uint32_t* __restrict__ cur,
                          uint32_t* __restrict__ sortedIdx, int n) {
  const int base = blockIdx.x * (256 * UNROLL) + threadIdx.x;
  const bool full = (blockIdx.x + 1) * (256 * UNROLL) <= n;
  if (full) {
    uint32_t kk[UNROLL], st[UNROLL];
#pragma unroll
    for (int u = 0; u < UNROLL; ++u) kk[u] = keys[base + u * 256];
#pragma unroll
    for (int u = 0; u < UNROLL; ++u) st[u] = cur[kk[u] & KMASK];
#pragma unroll
    for (int u = 0; u < UNROLL; ++u)
      sortedIdx[st[u] + (kk[u] >> 21)] = (uint32_t)(base + u * 256);
  } else {
    for (int u = 0; u < UNROLL; ++u) {
      int i = base + u * 256;
      if (i < n) {
        uint32_t kk = keys[i];
        sortedIdx[cur[kk & KMASK] + (kk >> 21)] = (uint32_t)i;
      }
    }
  }
}

// ---- pass 4: per-group mean; half-wave = 8 rows (two quad-sets A/B) --------
__global__ __launch_bounds__(256, 8)
void k_pool(const float* __restrict__ feats, const uint32_t* __restrict__ sortedIdx,
            const uint64_t* __restrict__ denseMeta, const uint32_t* __restrict__ totalK,
            float* __restrict__ outFeats, float* __restrict__ uniqOut, int n) {
  const int tid = threadIdx.x;
  const int hw = tid >> 5;
  const int lane = tid & 31;
  const int subrow = lane >> 3;
  const int cl = lane & 7;
  const uint32_t K = *totalK;
  const int j0 = (blockIdx.x * 8 + hw) * 8;
  const int jA = j0 + subrow;
  const int jB = j0 + 4 + subrow;

  const bool vA = jA < n, vB = jB < n;
  const bool lA = vA && (uint32_t)jA < K;
  const bool lB = vB && (uint32_t)jB < K;

  uint32_t sA = 0, cA = 0, sB = 0, cB = 0;
  if (lA) { uint64_t dm = denseMeta[jA]; sA = (uint32_t)dm; cA = (uint32_t)(dm >> 32); }
  if (lB) { uint64_t dm = denseMeta[jB]; sB = (uint32_t)dm; cB = (uint32_t)(dm >> 32); }

  uint32_t iA = 0, iB = 0;
  if (lA && (uint32_t)cl < cA) iA = sortedIdx[sA + (uint32_t)cl];
  if (lB && (uint32_t)cl < cB) iB = sortedIdx[sB + (uint32_t)cl];

  vf4 aA = {0.f, 0.f, 0.f, 0.f}, aB = {0.f, 0.f, 0.f, 0.f};
#pragma unroll
  for (int q = 0; q < 4; ++q) {
    uint32_t uA = (uint32_t)__shfl((int)iA, (subrow << 3) | q, 32);
    uint32_t uB = (uint32_t)__shfl((int)iB, (subrow << 3) | q, 32);
    vf4 xA = *(const vf4*)(feats + (size_t)uA * C + cl * 4);
    vf4 xB = *(const vf4*)(feats + (size_t)uB * C + cl * 4);
    aA += ((uint32_t)q < cA) ? xA : (vf4){0.f, 0.f, 0.f, 0.f};
    aB += ((uint32_t)q < cB) ? xB : (vf4){0.f, 0.f, 0.f, 0.f};
  }
  for (uint32_t q = 4; q < 8u; ++q) {
    if (__all((int)(q >= cA && q >= cB))) break;
    uint32_t uA = (uint32_t)__shfl((int)iA, (int)(((uint32_t)subrow << 3) | q), 32);
    uint32_t uB = (uint32_t)__shfl((int)iB, (int)(((uint32_t)subrow << 3) | q), 32);
    if (q < cA) aA += *(const vf4*)(feats + (size_t)uA * C + cl * 4);
    if (q < cB) aB += *(const vf4*)(feats + (size_t)uB * C + cl * 4);
  }
  if (__any((int)(cA > 8u || cB > 8u))) {
    for (uint32_t q = 8; q < cA; ++q)
      aA += *(const vf4*)(feats + (size_t)sortedIdx[sA + q] * C + cl * 4);
    for (uint32_t q = 8; q < cB; ++q)
      aB += *(const vf4*)(feats + (size_t)sortedIdx[sB + q] * C + cl * 4);
  }

  if (vA) {
    float inv = lA ? 1.0f / (float)cA : 0.0f;
    vf4 o = aA * inv;
    __builtin_nontemporal_store(o, (vf4*)(outFeats + (size_t)jA * C + cl * 4));
    if (!lA && cl == 0) uniqOut[jA] = -1.0f;
  }
  if (vB) {
    float inv = lB ? 1.0f / (float)cB : 0.0f;
    vf4 o = aB * inv;
    __builtin_nontemporal_store(o, (vf4*)(outFeats + (size_t)jB * C + cl * 4));
    if (!lB && cl == 0) uniqOut[jB] = -1.0f;
  }
}

extern "C" void kernel_launch(void* const* d_in, const int* in_sizes, int n_in,
                              void* d_out, int out_size, void* d_ws, size_t ws_size,
                              hipStream_t stream) {
  const float* feats = (const float*)d_in[0];
  const int4* coords = (const int4*)d_in[1];
  int n = in_sizes[0] / C;   // N = 2,000,000

  char* ws = (char*)d_ws;
  const size_t MB = 1024u * 1024u;
  uint32_t* keys      = (uint32_t*)(ws + 0 * MB);
  uint32_t* cnt       = (uint32_t*)(ws + 8 * MB);
  uint32_t* cur       = (uint32_t*)(ws + 16 * MB);
  uint64_t* denseMeta = (uint64_t*)(ws + 24 * MB);
  uint32_t* sortedIdx = (uint32_t*)(ws + 40 * MB);
  uint32_t* blkP      = (uint32_t*)(ws + 48 * MB);
  uint32_t* blkM      = blkP + NBLK;
  uint32_t* totalK    = blkM + NBLK;

  float* outFeats = (float*)d_out;
  float* uniqOut  = outFeats + (size_t)n * C;

  void* cargs[] = {(void*)&coords, (void*)&keys, (void*)&cnt, (void*)&cur,
                   (void*)&denseMeta, (void*)&uniqOut, (void*)&totalK,
                   (void*)&sortedIdx, (void*)&blkP, (void*)&blkM, (void*)&n};
  hipError_t e = hipLaunchCooperativeKernel((void*)coop_prep, dim3(NBLK), dim3(TPB),
                                            cargs, 0, stream);
  if (e != hipSuccess) {
    // deterministic fallback: proven 5-kernel chain
    int chunk = 256 * UNROLL;
    k_zero<<<KS / 4 / 256, 256, 0, stream>>>((uint4*)cnt, KS / 4);
    k_count<<<(n + chunk - 1) / chunk, 256, 0, stream>>>(coords, keys, cnt, n);
    k_blocksum<<<NBLK, TPB, 0, stream>>>(cnt, blkP, blkM);
    k_finalize<<<NBLK, TPB, 0, stream>>>(cnt, blkP, blkM, cur, denseMeta, uniqOut, totalK);
    k_scatter<<<(n + chunk - 1) / chunk, 256, 0, stream>>>(keys, cur, sortedIdx, n);
  }
  k_pool<<<(n + 63) / 64, 256, 0, stream>>>(feats, sortedIdx, denseMeta, totalK, outFeats, uniqOut, n);
}

// Round 10
// 255.054 us; speedup vs baseline: 2.6990x; 2.6990x over previous
//
#include <hip/hip_runtime.h>
#include <stdint.h>

// Sparse 3D avg-pool, kernel=stride=2, GRID=128, B=8, C=32.
// Keyspace = 8*64^3 = 2^21 -> dense histogram + scan instead of sort/unique.
// Round 10: REVERT to the proven R8 structure (254.9 us). The R9 cooperative
// fusion was a 10x regression: grid.sync() with 1024 blocks costs ~100us each
// on MI355X -- multi-kernel dispatch chains are far cheaper than software
// grid barriers. Prep chain is L2/atomic-throughput-bound; k_pool is at the
// random-128B-gather bound.

#define KS (1u << 21)            // 2,097,152 possible keys
#define KMASK (KS - 1u)
#define SCAN_BLOCKS 1024
#define SCAN_TPB 256
#define EPT 8                    // elems per thread: 256*8=2048/block, *1024 = 2^21
#define C 32
#define UNROLL 8

typedef float vf4 __attribute__((ext_vector_type(4)));

// ---- pass 0: zero the histogram --------------------------------------------
__global__ void k_zero(uint4* __restrict__ p, int n4) {
  int i = blockIdx.x * blockDim.x + threadIdx.x;
  if (i < n4) p[i] = make_uint4(0u, 0u, 0u, 0u);
}

// ---- pass 1: key per voxel + dense histogram; rank packed in key bits ------
__global__ void k_count(const int4* __restrict__ coords, uint32_t* __restrict__ keys,
                        uint32_t* __restrict__ cnt, int n) {
  const int base = blockIdx.x * (256 * UNROLL) + threadIdx.x;
  const bool full = (blockIdx.x + 1) * (256 * UNROLL) <= n;
  if (full) {
    int4 cc[UNROLL];
    uint32_t k[UNROLL], r[UNROLL];
#pragma unroll
    for (int u = 0; u < UNROLL; ++u) cc[u] = coords[base + u * 256];
#pragma unroll
    for (int u = 0; u < UNROLL; ++u)
      k[u] = (((uint32_t)cc[u].x * 64u + ((uint32_t)cc[u].y >> 1)) * 64u
              + ((uint32_t)cc[u].z >> 1)) * 64u + ((uint32_t)cc[u].w >> 1);
#pragma unroll
    for (int u = 0; u < UNROLL; ++u) r[u] = atomicAdd(&cnt[k[u]], 1u);
#pragma unroll
    for (int u = 0; u < UNROLL; ++u) keys[base + u * 256] = k[u] | (r[u] << 21);
  } else {
    for (int u = 0; u < UNROLL; ++u) {
      int i = base + u * 256;
      if (i < n) {
        int4 cc = coords[i];
        uint32_t k = (((uint32_t)cc.x * 64u + ((uint32_t)cc.y >> 1)) * 64u
                      + ((uint32_t)cc.z >> 1)) * 64u + ((uint32_t)cc.w >> 1);
        uint32_t r = atomicAdd(&cnt[k], 1u);
        keys[i] = k | (r << 21);
      }
    }
  }
}

// ---- pass 2a: per-block sums of (presence, count) --------------------------
__global__ void k_blocksum(const uint32_t* __restrict__ cnt,
                           uint32_t* __restrict__ blkP, uint32_t* __restrict__ blkM) {
  __shared__ uint32_t sp[SCAN_TPB], sm[SCAN_TPB];
  int t = threadIdx.x;
  int base = blockIdx.x * (SCAN_TPB * EPT) + t * EPT;
  const uint4* c4 = (const uint4*)(cnt + base);
  uint4 q0 = c4[0], q1 = c4[1];
  uint32_t p = (q0.x > 0) + (q0.y > 0) + (q0.z > 0) + (q0.w > 0)
             + (q1.x > 0) + (q1.y > 0) + (q1.z > 0) + (q1.w > 0);
  uint32_t m = q0.x + q0.y + q0.z + q0.w + q1.x + q1.y + q1.z + q1.w;
  sp[t] = p; sm[t] = m;
  __syncthreads();
  for (int off = SCAN_TPB / 2; off > 0; off >>= 1) {
    if (t < off) { sp[t] += sp[t + off]; sm[t] += sm[t + off]; }
    __syncthreads();
  }
  if (t == 0) { blkP[blockIdx.x] = sp[0]; blkM[blockIdx.x] = sm[0]; }
}

// ---- pass 2b: finalize (scan folded in: per-block reduction of partials) ---
__global__ void k_finalize(const uint32_t* __restrict__ cnt,
                           const uint32_t* __restrict__ blkP, const uint32_t* __restrict__ blkM,
                           uint32_t* __restrict__ cur,
                           uint64_t* __restrict__ denseMeta,
                           float* __restrict__ uniqOut,
                           uint32_t* __restrict__ totalK) {
  __shared__ uint64_t rAll[SCAN_TPB], rBel[SCAN_TPB];
  __shared__ uint32_t sp[SCAN_TPB], sm[SCAN_TPB];
  const int t = threadIdx.x;
  const int b = blockIdx.x;

  uint64_t all = 0, bel = 0;
  for (int u = t; u < SCAN_BLOCKS; u += SCAN_TPB) {
    uint64_t v = ((uint64_t)blkP[u] << 32) | (uint64_t)blkM[u];
    all += v;
    if (u < b) bel += v;
  }
  rAll[t] = all; rBel[t] = bel;
  __syncthreads();
  for (int off = SCAN_TPB / 2; off > 0; off >>= 1) {
    if (t < off) { rAll[t] += rAll[t + off]; rBel[t] += rBel[t + off]; }
    __syncthreads();
  }
  const uint32_t blockP = (uint32_t)(rBel[0] >> 32);
  const uint32_t blockM = (uint32_t)rBel[0];
  if (b == 0 && t == 0) *totalK = (uint32_t)(rAll[0] >> 32);

  int base = b * (SCAN_TPB * EPT) + t * EPT;
  const uint4* c4 = (const uint4*)(cnt + base);
  uint4 q0 = c4[0], q1 = c4[1];
  uint32_t c[EPT] = {q0.x, q0.y, q0.z, q0.w, q1.x, q1.y, q1.z, q1.w};
  uint32_t p = 0, m = 0;
#pragma unroll
  for (int e = 0; e < EPT; e++) { p += (c[e] > 0); m += c[e]; }
  __syncthreads();
  sp[t] = p; sm[t] = m;
  __syncthreads();
  for (int off = 1; off < SCAN_TPB; off <<= 1) {
    uint32_t vp = (t >= off) ? sp[t - off] : 0u;
    uint32_t vm = (t >= off) ? sm[t - off] : 0u;
    __syncthreads();
    sp[t] += vp; sm[t] += vm;
    __syncthreads();
  }
  uint32_t poff = blockP + (t ? sp[t - 1] : 0u);
  uint32_t moff = blockM + (t ? sm[t - 1] : 0u);
#pragma unroll
  for (int e = 0; e < EPT; e++) {
    if (c[e] > 0) {
      uint32_t k = (uint32_t)base + (uint32_t)e;
      cur[k] = moff;                               // group start
      denseMeta[poff] = ((uint64_t)c[e] << 32) | (uint64_t)moff;
      uniqOut[poff]   = (float)k;                  // exact in f32 (< 2^24)
      poff++;
    }
    moff += c[e];
  }
}

// ---- pass 3: atomic-free counting-sort placement, phase-split ---------------
__global__ void k_scatter(const uint32_t* __restrict__ keys, const uint32_t* __restrict__ cur,
                          uint32_t* __restrict__ sortedIdx, int n) {
  const int base = blockIdx.x * (256 * UNROLL) + threadIdx.x;
  const bool full = (blockIdx.x + 1) * (256 * UNROLL) <= n;
  if (full) {
    uint32_t kk[UNROLL], st[UNROLL];
#pragma unroll
    for (int u = 0; u < UNROLL; ++u) kk[u] = keys[base + u * 256];
#pragma unroll
    for (int u = 0; u < UNROLL; ++u) st[u] = cur[kk[u] & KMASK];
#pragma unroll
    for (int u = 0; u < UNROLL; ++u)
      sortedIdx[st[u] + (kk[u] >> 21)] = (uint32_t)(base + u * 256);
  } else {
    for (int u = 0; u < UNROLL; ++u) {
      int i = base + u * 256;
      if (i < n) {
        uint32_t kk = keys[i];
        sortedIdx[cur[kk & KMASK] + (kk >> 21)] = (uint32_t)i;
      }
    }
  }
}

// ---- pass 4: per-group mean; half-wave = 8 rows (two quad-sets A/B) --------
__global__ __launch_bounds__(256, 8)
void k_pool(const float* __restrict__ feats, const uint32_t* __restrict__ sortedIdx,
            const uint64_t* __restrict__ denseMeta, const uint32_t* __restrict__ totalK,
            float* __restrict__ outFeats, float* __restrict__ uniqOut, int n) {
  const int tid = threadIdx.x;
  const int hw = tid >> 5;              // half-wave 0..7
  const int lane = tid & 31;
  const int subrow = lane >> 3;         // 0..3
  const int cl = lane & 7;              // float4 column
  const uint32_t K = *totalK;
  const int j0 = (blockIdx.x * 8 + hw) * 8;     // 8 consecutive rows
  const int jA = j0 + subrow;
  const int jB = j0 + 4 + subrow;

  const bool vA = jA < n, vB = jB < n;
  const bool lA = vA && (uint32_t)jA < K;
  const bool lB = vB && (uint32_t)jB < K;

  uint32_t sA = 0, cA = 0, sB = 0, cB = 0;
  if (lA) { uint64_t dm = denseMeta[jA]; sA = (uint32_t)dm; cA = (uint32_t)(dm >> 32); }
  if (lB) { uint64_t dm = denseMeta[jB]; sB = (uint32_t)dm; cB = (uint32_t)(dm >> 32); }

  uint32_t iA = 0, iB = 0;              // member cl of my row (up to 8 prefetched)
  if (lA && (uint32_t)cl < cA) iA = sortedIdx[sA + (uint32_t)cl];
  if (lB && (uint32_t)cl < cB) iB = sortedIdx[sB + (uint32_t)cl];

  vf4 aA = {0.f, 0.f, 0.f, 0.f}, aB = {0.f, 0.f, 0.f, 0.f};
  // 8 straight-line gathers, no branches between loads -> all in flight.
#pragma unroll
  for (int q = 0; q < 4; ++q) {
    uint32_t uA = (uint32_t)__shfl((int)iA, (subrow << 3) | q, 32);
    uint32_t uB = (uint32_t)__shfl((int)iB, (subrow << 3) | q, 32);
    vf4 xA = *(const vf4*)(feats + (size_t)uA * C + cl * 4);
    vf4 xB = *(const vf4*)(feats + (size_t)uB * C + cl * 4);
    aA += ((uint32_t)q < cA) ? xA : (vf4){0.f, 0.f, 0.f, 0.f};
    aB += ((uint32_t)q < cB) ? xB : (vf4){0.f, 0.f, 0.f, 0.f};
  }
  // tail to c<=8 (~0.5% of rows): union vote across both sets
  for (uint32_t q = 4; q < 8u; ++q) {
    if (__all((int)(q >= cA && q >= cB))) break;
    uint32_t uA = (uint32_t)__shfl((int)iA, (int)(((uint32_t)subrow << 3) | q), 32);
    uint32_t uB = (uint32_t)__shfl((int)iB, (int)(((uint32_t)subrow << 3) | q), 32);
    if (q < cA) aA += *(const vf4*)(feats + (size_t)uA * C + cl * 4);
    if (q < cB) aB += *(const vf4*)(feats + (size_t)uB * C + cl * 4);
  }
  // essentially-never fallback for c>8
  if (__any((int)(cA > 8u || cB > 8u))) {
    for (uint32_t q = 8; q < cA; ++q)
      aA += *(const vf4*)(feats + (size_t)sortedIdx[sA + q] * C + cl * 4);
    for (uint32_t q = 8; q < cB; ++q)
      aB += *(const vf4*)(feats + (size_t)sortedIdx[sB + q] * C + cl * 4);
  }

  if (vA) {
    float inv = lA ? 1.0f / (float)cA : 0.0f;
    vf4 o = aA * inv;
    __builtin_nontemporal_store(o, (vf4*)(outFeats + (size_t)jA * C + cl * 4));
    if (!lA && cl == 0) uniqOut[jA] = -1.0f;
  }
  if (vB) {
    float inv = lB ? 1.0f / (float)cB : 0.0f;
    vf4 o = aB * inv;
    __builtin_nontemporal_store(o, (vf4*)(outFeats + (size_t)jB * C + cl * 4));
    if (!lB && cl == 0) uniqOut[jB] = -1.0f;
  }
}

extern "C" void kernel_launch(void* const* d_in, const int* in_sizes, int n_in,
                              void* d_out, int out_size, void* d_ws, size_t ws_size,
                              hipStream_t stream) {
  const float* feats = (const float*)d_in[0];
  const int4* coords = (const int4*)d_in[1];
  int n = in_sizes[0] / C;   // N = 2,000,000

  char* ws = (char*)d_ws;
  const size_t MB = 1024u * 1024u;
  uint32_t* keys      = (uint32_t*)(ws + 0 * MB);    // n u32   (8 MB) key|rank<<21
  uint32_t* cnt       = (uint32_t*)(ws + 8 * MB);    // KS u32  (8 MB)
  uint32_t* cur       = (uint32_t*)(ws + 16 * MB);   // KS u32  (8 MB) group starts
  uint64_t* denseMeta = (uint64_t*)(ws + 24 * MB);   // <=n u64 (16 MB) {cnt,start}
  uint32_t* sortedIdx = (uint32_t*)(ws + 40 * MB);   // n u32   (8 MB)
  uint32_t* blkP      = (uint32_t*)(ws + 48 * MB);   // 1024 u32
  uint32_t* blkM      = blkP + SCAN_BLOCKS;          // 1024 u32
  uint32_t* totalK    = blkM + SCAN_BLOCKS;          // 1 u32

  float* outFeats = (float*)d_out;                   // [n, 32]
  float* uniqOut  = outFeats + (size_t)n * C;        // [n] keys as f32

  int chunk = 256 * UNROLL;
  k_zero<<<KS / 4 / 256, 256, 0, stream>>>((uint4*)cnt, KS / 4);
  k_count<<<(n + chunk - 1) / chunk, 256, 0, stream>>>(coords, keys, cnt, n);
  k_blocksum<<<SCAN_BLOCKS, SCAN_TPB, 0, stream>>>(cnt, blkP, blkM);
  k_finalize<<<SCAN_BLOCKS, SCAN_TPB, 0, stream>>>(cnt, blkP, blkM, cur, denseMeta, uniqOut, totalK);
  k_scatter<<<(n + chunk - 1) / chunk, 256, 0, stream>>>(keys, cur, sortedIdx, n);
  k_pool<<<(n + 63) / 64, 256, 0, stream>>>(feats, sortedIdx, denseMeta, totalK, outFeats, uniqOut, n);
}